// Round 1
// baseline (714.815 us; speedup 1.0000x reference)
//
#include <hip/hip_runtime.h>

#define N_OP   50000
#define N_MAC  2000
#define IN_OP  64
#define IN_MAC 32
#define OUT    128
#define HEADS  4
#define DK     32
#define ATT_DIM 65
#define E_SEQ  150000
#define E_OM   300000
#define E_MO   300000
#define EPS    1e-6f
#define LN_EPS 1e-5f

// ---------------------------------------------------------------------------
// GEMM for op nodes: z = h @ W^T + b  (h: [N,64], W: [128,64]) plus fused
// attention-projection epilogue:
//   a_seq_src = dot(z[h], att_seq[h, 0:32])
//   a_seq_dst = dot(z[h], att_seq[h,32:64])
//   a_om_src  = dot(z[h], att_om [h, 0:32])
//   a_mo_dst  = dot(z[h], att_mo [h,32:64])
// One 128-thread block per row; thread t owns output column t.
// ---------------------------------------------------------------------------
__global__ void k_gemm_op(const float* __restrict__ h, const float* __restrict__ W,
                          const float* __restrict__ b,
                          const float* __restrict__ att_seq,
                          const float* __restrict__ att_om,
                          const float* __restrict__ att_mo,
                          float* __restrict__ z,
                          float* __restrict__ a_seq_src, float* __restrict__ a_seq_dst,
                          float* __restrict__ a_om_src,  float* __restrict__ a_mo_dst) {
    const int row = blockIdx.x;
    const int t = threadIdx.x;
    __shared__ float hs[IN_OP];
    if (t < IN_OP) hs[t] = h[(size_t)row * IN_OP + t];
    __syncthreads();

    const float4* Wv = reinterpret_cast<const float4*>(W + t * IN_OP);
    const float4* hv = reinterpret_cast<const float4*>(hs);
    float acc = b[t];
#pragma unroll
    for (int k = 0; k < IN_OP / 4; ++k) {
        float4 w4 = Wv[k];
        float4 h4 = hv[k];
        acc += w4.x * h4.x + w4.y * h4.y + w4.z * h4.z + w4.w * h4.w;
    }
    z[(size_t)row * OUT + t] = acc;

    const int hd = t >> 5, l = t & 31;
    float p1 = acc * att_seq[hd * ATT_DIM + l];
    float p2 = acc * att_seq[hd * ATT_DIM + 32 + l];
    float p3 = acc * att_om[hd * ATT_DIM + l];
    float p4 = acc * att_mo[hd * ATT_DIM + 32 + l];
#pragma unroll
    for (int m = 16; m >= 1; m >>= 1) {
        p1 += __shfl_xor(p1, m);
        p2 += __shfl_xor(p2, m);
        p3 += __shfl_xor(p3, m);
        p4 += __shfl_xor(p4, m);
    }
    if (l == 0) {
        a_seq_src[row * HEADS + hd] = p1;
        a_seq_dst[row * HEADS + hd] = p2;
        a_om_src[row * HEADS + hd]  = p3;
        a_mo_dst[row * HEADS + hd]  = p4;
    }
}

// GEMM for mac nodes (K=32) + epilogue for mac-side projections:
//   a_om_dst = dot(z[h], att_om[h,32:64]),  a_mo_src = dot(z[h], att_mo[h,0:32])
__global__ void k_gemm_mac(const float* __restrict__ h, const float* __restrict__ W,
                           const float* __restrict__ b,
                           const float* __restrict__ att_om,
                           const float* __restrict__ att_mo,
                           float* __restrict__ z,
                           float* __restrict__ a_om_dst, float* __restrict__ a_mo_src) {
    const int row = blockIdx.x;
    const int t = threadIdx.x;
    __shared__ float hs[IN_MAC];
    if (t < IN_MAC) hs[t] = h[(size_t)row * IN_MAC + t];
    __syncthreads();

    const float4* Wv = reinterpret_cast<const float4*>(W + t * IN_MAC);
    const float4* hv = reinterpret_cast<const float4*>(hs);
    float acc = b[t];
#pragma unroll
    for (int k = 0; k < IN_MAC / 4; ++k) {
        float4 w4 = Wv[k];
        float4 h4 = hv[k];
        acc += w4.x * h4.x + w4.y * h4.y + w4.z * h4.z + w4.w * h4.w;
    }
    z[(size_t)row * OUT + t] = acc;

    const int hd = t >> 5, l = t & 31;
    float p1 = acc * att_om[hd * ATT_DIM + 32 + l];
    float p2 = acc * att_mo[hd * ATT_DIM + l];
#pragma unroll
    for (int m = 16; m >= 1; m >>= 1) {
        p1 += __shfl_xor(p1, m);
        p2 += __shfl_xor(p2, m);
    }
    if (l == 0) {
        a_om_dst[row * HEADS + hd] = p1;
        a_mo_src[row * HEADS + hd] = p2;
    }
}

// ---------------------------------------------------------------------------
// Per-edge: score = a_src[s,h] + a_dst[d,h] + feat[e]*att[h,64]
//           alpha = exp(clip(leaky_relu(score, 0.2), -20, 20))
// Store alpha[e,h]; atomically accumulate denom[d,h].
// ---------------------------------------------------------------------------
__global__ void k_edge_alpha(const int* __restrict__ src, const int* __restrict__ dst,
                             const float* __restrict__ feat,
                             const float* __restrict__ a_src, const float* __restrict__ a_dst,
                             const float* __restrict__ att,
                             float* __restrict__ alpha, float* __restrict__ denom, int E) {
    const int e = blockIdx.x * blockDim.x + threadIdx.x;
    if (e >= E) return;
    const int s = src[e], d = dst[e];
    const float f = feat[e];
    const float4 as = *reinterpret_cast<const float4*>(a_src + s * HEADS);
    const float4 ad = *reinterpret_cast<const float4*>(a_dst + d * HEADS);
    float sc[HEADS] = {as.x + ad.x, as.y + ad.y, as.z + ad.z, as.w + ad.w};
#pragma unroll
    for (int h = 0; h < HEADS; ++h) {
        float v = sc[h] + f * att[h * ATT_DIM + 2 * DK];
        v = (v >= 0.f) ? v : 0.2f * v;   // leaky_relu 0.2
        v = fminf(fmaxf(v, -20.f), 20.f);
        v = expf(v);
        alpha[(size_t)e * HEADS + h] = v;
        atomicAdd(&denom[d * HEADS + h], v);
    }
}

// ---------------------------------------------------------------------------
// Weighted scatter: out[d, r] += z_src[s, r] * alpha[e,h]/(denom[d,h]+EPS)
// 128 threads per edge (thread r owns column r, h = r>>5). Coalesced gather +
// coalesced atomics.
// ---------------------------------------------------------------------------
__global__ void k_scatter(const int* __restrict__ src, const int* __restrict__ dst,
                          const float* __restrict__ alpha, const float* __restrict__ denom,
                          const float* __restrict__ zsrc, float* __restrict__ outacc, int E) {
    const int idx = blockIdx.x * blockDim.x + threadIdx.x;
    if (idx >= E * OUT) return;
    const int e = idx >> 7;
    const int r = idx & 127;
    const int h = r >> 5;
    const int s = src[e], d = dst[e];
    const float w = alpha[(size_t)e * HEADS + h] / (denom[d * HEADS + h] + EPS);
    atomicAdd(&outacc[(size_t)d * OUT + r], zsrc[(size_t)s * OUT + r] * w);
}

// ---------------------------------------------------------------------------
// Finalize: x = acc + z (residual); LayerNorm over 128; ELU; write in place.
// One 128-thread block per row.
// ---------------------------------------------------------------------------
__global__ void k_finalize(const float* __restrict__ z,
                           const float* __restrict__ g, const float* __restrict__ bb,
                           float* __restrict__ out) {
    const int row = blockIdx.x;
    const int t = threadIdx.x;
    float x = out[(size_t)row * OUT + t] + z[(size_t)row * OUT + t];

    __shared__ float red1[2], red2[2];
    float s = x;
#pragma unroll
    for (int m = 32; m >= 1; m >>= 1) s += __shfl_xor(s, m);
    if ((t & 63) == 0) red1[t >> 6] = s;
    __syncthreads();
    const float mu = (red1[0] + red1[1]) * (1.0f / OUT);

    const float dx = x - mu;
    float q = dx * dx;
#pragma unroll
    for (int m = 32; m >= 1; m >>= 1) q += __shfl_xor(q, m);
    if ((t & 63) == 0) red2[t >> 6] = q;
    __syncthreads();
    const float var = (red2[0] + red2[1]) * (1.0f / OUT);

    float y = dx * rsqrtf(var + LN_EPS) * g[t] + bb[t];
    y = (y > 0.f) ? y : (expf(y) - 1.0f);   // ELU, alpha=1
    out[(size_t)row * OUT + t] = y;
}

extern "C" void kernel_launch(void* const* d_in, const int* in_sizes, int n_in,
                              void* d_out, int out_size, void* d_ws, size_t ws_size,
                              hipStream_t stream) {
    const float* h_op      = (const float*)d_in[0];
    const float* h_mac     = (const float*)d_in[1];
    const int*   seq_src   = (const int*)d_in[2];
    const int*   seq_dst   = (const int*)d_in[3];
    const int*   om_src    = (const int*)d_in[4];
    const int*   om_dst    = (const int*)d_in[5];
    const int*   mo_src    = (const int*)d_in[6];
    const int*   mo_dst    = (const int*)d_in[7];
    const float* feat_seq  = (const float*)d_in[8];
    const float* feat_om   = (const float*)d_in[9];
    const float* feat_mo   = (const float*)d_in[10];
    const float* W_op_w    = (const float*)d_in[11];
    const float* W_op_b    = (const float*)d_in[12];
    const float* W_mac_w   = (const float*)d_in[13];
    const float* W_mac_b   = (const float*)d_in[14];
    const float* att_seq   = (const float*)d_in[15];
    const float* att_om    = (const float*)d_in[16];
    const float* att_mo    = (const float*)d_in[17];
    const float* ln_op_g   = (const float*)d_in[18];
    const float* ln_op_b   = (const float*)d_in[19];
    const float* ln_mac_g  = (const float*)d_in[20];
    const float* ln_mac_b  = (const float*)d_in[21];

    float* p = (float*)d_ws;
    float* z_op      = p; p += (size_t)N_OP * OUT;
    float* z_mac     = p; p += (size_t)N_MAC * OUT;
    float* a_seq_src = p; p += N_OP * HEADS;
    float* a_seq_dst = p; p += N_OP * HEADS;
    float* a_om_src  = p; p += N_OP * HEADS;
    float* a_mo_dst  = p; p += N_OP * HEADS;
    float* a_om_dst  = p; p += N_MAC * HEADS;
    float* a_mo_src  = p; p += N_MAC * HEADS;
    float* denom_seq = p; p += N_OP * HEADS;
    float* denom_mo  = p; p += N_OP * HEADS;
    float* denom_om  = p; p += N_MAC * HEADS;
    float* alpha_seq = p; p += (size_t)E_SEQ * HEADS;
    float* alpha_om  = p; p += (size_t)E_OM * HEADS;
    float* alpha_mo  = p; p += (size_t)E_MO * HEADS;

    float* out_op  = (float*)d_out;                       // [N_OP, 128]
    float* out_mac = (float*)d_out + (size_t)N_OP * OUT;  // [N_MAC, 128]

    // Zero accumulators (harness does not re-poison between replays).
    hipMemsetAsync(d_out, 0, (size_t)(N_OP + N_MAC) * OUT * sizeof(float), stream);
    hipMemsetAsync(denom_seq, 0, (size_t)(2 * N_OP + N_MAC) * HEADS * sizeof(float), stream);

    // 1) Projections + fused attention-score projections.
    k_gemm_op<<<N_OP, 128, 0, stream>>>(h_op, W_op_w, W_op_b, att_seq, att_om, att_mo,
                                        z_op, a_seq_src, a_seq_dst, a_om_src, a_mo_dst);
    k_gemm_mac<<<N_MAC, 128, 0, stream>>>(h_mac, W_mac_w, W_mac_b, att_om, att_mo,
                                          z_mac, a_om_dst, a_mo_src);

    // 2) Per-edge alpha + denom.
    k_edge_alpha<<<(E_SEQ + 255) / 256, 256, 0, stream>>>(
        seq_src, seq_dst, feat_seq, a_seq_src, a_seq_dst, att_seq, alpha_seq, denom_seq, E_SEQ);
    k_edge_alpha<<<(E_MO + 255) / 256, 256, 0, stream>>>(
        mo_src, mo_dst, feat_mo, a_mo_src, a_mo_dst, att_mo, alpha_mo, denom_mo, E_MO);
    k_edge_alpha<<<(E_OM + 255) / 256, 256, 0, stream>>>(
        om_src, om_dst, feat_om, a_om_src, a_om_dst, att_om, alpha_om, denom_om, E_OM);

    // 3) Weighted scatter into output accumulators.
    k_scatter<<<(E_SEQ * OUT + 255) / 256, 256, 0, stream>>>(
        seq_src, seq_dst, alpha_seq, denom_seq, z_op, out_op, E_SEQ);
    k_scatter<<<(E_MO * OUT + 255) / 256, 256, 0, stream>>>(
        mo_src, mo_dst, alpha_mo, denom_mo, z_mac, out_op, E_MO);
    k_scatter<<<(E_OM * OUT + 255) / 256, 256, 0, stream>>>(
        om_src, om_dst, alpha_om, denom_om, z_op, out_mac, E_OM);

    // 4) Residual + LayerNorm + ELU (in place on d_out).
    k_finalize<<<N_OP, 128, 0, stream>>>(z_op, ln_op_g, ln_op_b, out_op);
    k_finalize<<<N_MAC, 128, 0, stream>>>(z_mac, ln_mac_g, ln_mac_b, out_mac);
}

// Round 2
// 391.211 us; speedup vs baseline: 1.8272x; 1.8272x over previous
//
#include <hip/hip_runtime.h>

#define N_OP   50000
#define N_MAC  2000
#define IN_OP  64
#define IN_MAC 32
#define OUT    128
#define HEADS  4
#define DK     32
#define ATT_DIM 65
#define E_SEQ  150000
#define E_OM   300000
#define E_MO   300000
#define EPS    1e-6f
#define LN_EPS 1e-5f

// ---------------------------------------------------------------------------
// GEMM op nodes: z = h @ W^T + b. 256 threads = 2 rows/iter, W column held in
// registers (16 float4), h rows broadcast from LDS. Fused epilogue computes
// the 4 attention projections per row via 32-lane shuffle reduce.
// ---------------------------------------------------------------------------
__global__ void k_gemm_op(const float* __restrict__ h, const float* __restrict__ W,
                          const float* __restrict__ b,
                          const float* __restrict__ att_seq,
                          const float* __restrict__ att_om,
                          const float* __restrict__ att_mo,
                          float* __restrict__ z,
                          float* __restrict__ a_seq_src, float* __restrict__ a_seq_dst,
                          float* __restrict__ a_om_src,  float* __restrict__ a_mo_dst) {
    const int t = threadIdx.x;
    const int col = t & 127;
    const int slot = t >> 7;
    float4 w[16];
    const float4* Wv = reinterpret_cast<const float4*>(W + col * IN_OP);
#pragma unroll
    for (int k = 0; k < 16; ++k) w[k] = Wv[k];
    const float bias = b[col];
    const int hd = col >> 5, l = col & 31;
    const float c1 = att_seq[hd * ATT_DIM + l];
    const float c2 = att_seq[hd * ATT_DIM + 32 + l];
    const float c3 = att_om[hd * ATT_DIM + l];
    const float c4 = att_mo[hd * ATT_DIM + 32 + l];
    __shared__ float hs[2][IN_OP];

    for (int row0 = blockIdx.x * 2; row0 < N_OP; row0 += gridDim.x * 2) {
        __syncthreads();
        if (t < 128) hs[t >> 6][t & 63] = h[(size_t)(row0 + (t >> 6)) * IN_OP + (t & 63)];
        __syncthreads();
        const float4* hv = reinterpret_cast<const float4*>(hs[slot]);
        float acc = bias;
#pragma unroll
        for (int k = 0; k < 16; ++k) {
            float4 h4 = hv[k];
            acc += w[k].x * h4.x + w[k].y * h4.y + w[k].z * h4.z + w[k].w * h4.w;
        }
        const int row = row0 + slot;
        z[(size_t)row * OUT + col] = acc;

        float p1 = acc * c1, p2 = acc * c2, p3 = acc * c3, p4 = acc * c4;
#pragma unroll
        for (int m = 16; m >= 1; m >>= 1) {
            p1 += __shfl_xor(p1, m);
            p2 += __shfl_xor(p2, m);
            p3 += __shfl_xor(p3, m);
            p4 += __shfl_xor(p4, m);
        }
        if (l == 0) {
            a_seq_src[row * HEADS + hd] = p1;
            a_seq_dst[row * HEADS + hd] = p2;
            a_om_src[row * HEADS + hd]  = p3;
            a_mo_dst[row * HEADS + hd]  = p4;
        }
    }
}

__global__ void k_gemm_mac(const float* __restrict__ h, const float* __restrict__ W,
                           const float* __restrict__ b,
                           const float* __restrict__ att_om,
                           const float* __restrict__ att_mo,
                           float* __restrict__ z,
                           float* __restrict__ a_om_dst, float* __restrict__ a_mo_src) {
    const int t = threadIdx.x;
    const int col = t & 127;
    const int slot = t >> 7;
    float4 w[8];
    const float4* Wv = reinterpret_cast<const float4*>(W + col * IN_MAC);
#pragma unroll
    for (int k = 0; k < 8; ++k) w[k] = Wv[k];
    const float bias = b[col];
    const int hd = col >> 5, l = col & 31;
    const float c1 = att_om[hd * ATT_DIM + 32 + l];
    const float c2 = att_mo[hd * ATT_DIM + l];
    __shared__ float hs[2][IN_MAC];

    for (int row0 = blockIdx.x * 2; row0 < N_MAC; row0 += gridDim.x * 2) {
        __syncthreads();
        if (t < 64) hs[t >> 5][t & 31] = h[(size_t)(row0 + (t >> 5)) * IN_MAC + (t & 31)];
        __syncthreads();
        const float4* hv = reinterpret_cast<const float4*>(hs[slot]);
        float acc = bias;
#pragma unroll
        for (int k = 0; k < 8; ++k) {
            float4 h4 = hv[k];
            acc += w[k].x * h4.x + w[k].y * h4.y + w[k].z * h4.z + w[k].w * h4.w;
        }
        const int row = row0 + slot;
        z[(size_t)row * OUT + col] = acc;

        float p1 = acc * c1, p2 = acc * c2;
#pragma unroll
        for (int m = 16; m >= 1; m >>= 1) {
            p1 += __shfl_xor(p1, m);
            p2 += __shfl_xor(p2, m);
        }
        if (l == 0) {
            a_om_dst[row * HEADS + hd] = p1;
            a_mo_src[row * HEADS + hd] = p2;
        }
    }
}

// ---------------------------------------------------------------------------
// CSR build: histogram, 3-block scan, fill (records pos_of_e).
// ---------------------------------------------------------------------------
__global__ void k_count(const int* __restrict__ dst, int* __restrict__ cnt, int E) {
    int e = blockIdx.x * blockDim.x + threadIdx.x;
    if (e < E) atomicAdd(&cnt[dst[e]], 1);
}

// Exclusive prefix scan, one 1024-thread block per array (grid.x = 3).
__global__ void k_scan(int* __restrict__ cnt_seq, int* __restrict__ off_seq,
                       int* __restrict__ cnt_mo,  int* __restrict__ off_mo,
                       int* __restrict__ cnt_om,  int* __restrict__ off_om) {
    int* cnt; int* off; int n;
    if (blockIdx.x == 0)      { cnt = cnt_seq; off = off_seq; n = N_OP; }
    else if (blockIdx.x == 1) { cnt = cnt_mo;  off = off_mo;  n = N_OP; }
    else                      { cnt = cnt_om;  off = off_om;  n = N_MAC; }
    const int t = threadIdx.x, lane = t & 63, w = t >> 6;
    __shared__ int wsum[16];
    __shared__ int carry;
    if (t == 0) carry = 0;
    __syncthreads();
    for (int base = 0; base < n; base += 1024) {
        const int i = base + t;
        const int v = (i < n) ? cnt[i] : 0;
        int x = v;
#pragma unroll
        for (int m = 1; m < 64; m <<= 1) {
            int y = __shfl_up(x, m);
            if (lane >= m) x += y;
        }
        if (lane == 63) wsum[w] = x;
        __syncthreads();
        if (t == 0) {
            int s = carry;
            for (int k = 0; k < 16; ++k) { int c = wsum[k]; wsum[k] = s; s += c; }
            carry = s;
        }
        __syncthreads();
        if (i < n) off[i] = x - v + wsum[w];
        __syncthreads();
    }
}

__global__ void k_fill(const int* __restrict__ dst, int* __restrict__ off,
                       int* __restrict__ pos_of_e, int E) {
    int e = blockIdx.x * blockDim.x + threadIdx.x;
    if (e < E) pos_of_e[e] = atomicAdd(&off[dst[e]], 1);
}

// ---------------------------------------------------------------------------
// Per-edge alpha, written in BUCKET order (pos_of_e) so gather streams.
// score = a_src[s,h] + a_dst[d,h] + feat*att[h,64]; alpha=exp(clip(lrelu)).
// ---------------------------------------------------------------------------
__global__ void k_edge_alpha(const int* __restrict__ src, const int* __restrict__ dst,
                             const float* __restrict__ feat,
                             const float* __restrict__ a_src, const float* __restrict__ a_dst,
                             const float* __restrict__ att,
                             const int* __restrict__ pos_of_e,
                             float* __restrict__ alpha_bkt, int* __restrict__ bkt_s, int E) {
    const int e = blockIdx.x * blockDim.x + threadIdx.x;
    if (e >= E) return;
    const int s = src[e], d = dst[e];
    const int pos = pos_of_e[e];
    const float f = feat[e];
    const float4 as = *reinterpret_cast<const float4*>(a_src + s * HEADS);
    const float4 ad = *reinterpret_cast<const float4*>(a_dst + d * HEADS);
    const float sc[4] = {as.x + ad.x, as.y + ad.y, as.z + ad.z, as.w + ad.w};
    float4 out;
    float* o = &out.x;
#pragma unroll
    for (int hh = 0; hh < 4; ++hh) {
        float v = sc[hh] + f * att[hh * ATT_DIM + 2 * DK];
        v = (v >= 0.f) ? v : 0.2f * v;
        v = fminf(fmaxf(v, -20.f), 20.f);
        o[hh] = expf(v);
    }
    *reinterpret_cast<float4*>(alpha_bkt + (size_t)pos * HEADS) = out;
    bkt_s[pos] = s;
}

// ---------------------------------------------------------------------------
// LN + ELU epilogue helper (128 threads, 2 waves).
// ---------------------------------------------------------------------------
__device__ __forceinline__ float ln_elu(float x, int t, const float* __restrict__ g,
                                        const float* __restrict__ bb, float* red) {
    float s = x;
#pragma unroll
    for (int m = 32; m >= 1; m >>= 1) s += __shfl_xor(s, m);
    if ((t & 63) == 0) red[t >> 6] = s;
    __syncthreads();
    const float mu = (red[0] + red[1]) * (1.0f / OUT);
    const float dx = x - mu;
    float q = dx * dx;
#pragma unroll
    for (int m = 32; m >= 1; m >>= 1) q += __shfl_xor(q, m);
    __syncthreads();
    if ((t & 63) == 0) red[t >> 6] = q;
    __syncthreads();
    const float var = (red[0] + red[1]) * (1.0f / OUT);
    float y = dx * rsqrtf(var + LN_EPS) * g[t] + bb[t];
    return (y > 0.f) ? y : expm1f(y);
}

// ---------------------------------------------------------------------------
// Gather for op rows: two incoming graphs (seq from z_op, mo from z_mac),
// each independently normalized; + residual + LN + ELU.
// out[d] = sum_e(a*z_s)/(sum_e a + EPS) per graph. One 128-thr block per row.
// ---------------------------------------------------------------------------
__global__ void k_gather_op(const int* __restrict__ seq_s, const float* __restrict__ seq_a,
                            const int* __restrict__ seq_off, const int* __restrict__ seq_cnt,
                            const int* __restrict__ mo_s, const float* __restrict__ mo_a,
                            const int* __restrict__ mo_off, const int* __restrict__ mo_cnt,
                            const float* __restrict__ z_op, const float* __restrict__ z_mac,
                            const float* __restrict__ g, const float* __restrict__ bb,
                            float* __restrict__ out) {
    const int d = blockIdx.x;
    const int t = threadIdx.x;
    const int hd = t >> 5;
    __shared__ float red[2];
    float acc = 0.f;
    {
        const int end = seq_off[d];          // off was consumed by fill -> end
        const int start = end - seq_cnt[d];
        float num = 0.f, den = 0.f;
        for (int i = start; i < end; ++i) {
            const int s = seq_s[i];
            const float a = seq_a[(size_t)i * HEADS + hd];
            num += a * z_op[(size_t)s * OUT + t];
            den += a;
        }
        acc += num / (den + EPS);
    }
    {
        const int end = mo_off[d];
        const int start = end - mo_cnt[d];
        float num = 0.f, den = 0.f;
        for (int i = start; i < end; ++i) {
            const int s = mo_s[i];
            const float a = mo_a[(size_t)i * HEADS + hd];
            num += a * z_mac[(size_t)s * OUT + t];
            den += a;
        }
        acc += num / (den + EPS);
    }
    const float x = acc + z_op[(size_t)d * OUT + t];
    out[(size_t)d * OUT + t] = ln_elu(x, t, g, bb, red);
}

__global__ void k_gather_mac(const int* __restrict__ om_s, const float* __restrict__ om_a,
                             const int* __restrict__ om_off, const int* __restrict__ om_cnt,
                             const float* __restrict__ z_op, const float* __restrict__ z_mac,
                             const float* __restrict__ g, const float* __restrict__ bb,
                             float* __restrict__ out) {
    const int d = blockIdx.x;
    const int t = threadIdx.x;
    const int hd = t >> 5;
    __shared__ float red[2];
    float acc = 0.f;
    {
        const int end = om_off[d];
        const int start = end - om_cnt[d];
        float num = 0.f, den = 0.f;
        for (int i = start; i < end; ++i) {
            const int s = om_s[i];
            const float a = om_a[(size_t)i * HEADS + hd];
            num += a * z_op[(size_t)s * OUT + t];
            den += a;
        }
        acc = num / (den + EPS);
    }
    const float x = acc + z_mac[(size_t)d * OUT + t];
    out[(size_t)d * OUT + t] = ln_elu(x, t, g, bb, red);
}

extern "C" void kernel_launch(void* const* d_in, const int* in_sizes, int n_in,
                              void* d_out, int out_size, void* d_ws, size_t ws_size,
                              hipStream_t stream) {
    const float* h_op      = (const float*)d_in[0];
    const float* h_mac     = (const float*)d_in[1];
    const int*   seq_src   = (const int*)d_in[2];
    const int*   seq_dst   = (const int*)d_in[3];
    const int*   om_src    = (const int*)d_in[4];
    const int*   om_dst    = (const int*)d_in[5];
    const int*   mo_src    = (const int*)d_in[6];
    const int*   mo_dst    = (const int*)d_in[7];
    const float* feat_seq  = (const float*)d_in[8];
    const float* feat_om   = (const float*)d_in[9];
    const float* feat_mo   = (const float*)d_in[10];
    const float* W_op_w    = (const float*)d_in[11];
    const float* W_op_b    = (const float*)d_in[12];
    const float* W_mac_w   = (const float*)d_in[13];
    const float* W_mac_b   = (const float*)d_in[14];
    const float* att_seq   = (const float*)d_in[15];
    const float* att_om    = (const float*)d_in[16];
    const float* att_mo    = (const float*)d_in[17];
    const float* ln_op_g   = (const float*)d_in[18];
    const float* ln_op_b   = (const float*)d_in[19];
    const float* ln_mac_g  = (const float*)d_in[20];
    const float* ln_mac_b  = (const float*)d_in[21];

    float* p = (float*)d_ws;
    float* z_op      = p; p += (size_t)N_OP * OUT;
    float* z_mac     = p; p += (size_t)N_MAC * OUT;
    float* a_seq_src = p; p += N_OP * HEADS;
    float* a_seq_dst = p; p += N_OP * HEADS;
    float* a_om_src  = p; p += N_OP * HEADS;
    float* a_mo_dst  = p; p += N_OP * HEADS;
    float* a_om_dst  = p; p += N_MAC * HEADS;
    float* a_mo_src  = p; p += N_MAC * HEADS;
    float* alpha_seq = p; p += (size_t)E_SEQ * HEADS;
    float* alpha_mo  = p; p += (size_t)E_MO * HEADS;
    float* alpha_om  = p; p += (size_t)E_OM * HEADS;
    int* q = (int*)p;
    int* cnt_seq = q; q += N_OP;     // cnt_* contiguous for one memset
    int* cnt_mo  = q; q += N_OP;
    int* cnt_om  = q; q += N_MAC;
    int* off_seq = q; q += N_OP;
    int* off_mo  = q; q += N_OP;
    int* off_om  = q; q += N_MAC;
    int* pos_seq = q; q += E_SEQ;
    int* pos_mo  = q; q += E_MO;
    int* pos_om  = q; q += E_OM;
    int* bs_seq  = q; q += E_SEQ;
    int* bs_mo   = q; q += E_MO;
    int* bs_om   = q; q += E_OM;

    float* out_op  = (float*)d_out;
    float* out_mac = (float*)d_out + (size_t)N_OP * OUT;

    // CSR build.
    hipMemsetAsync(cnt_seq, 0, (size_t)(2 * N_OP + N_MAC) * sizeof(int), stream);
    k_count<<<(E_SEQ + 255) / 256, 256, 0, stream>>>(seq_dst, cnt_seq, E_SEQ);
    k_count<<<(E_MO + 255) / 256, 256, 0, stream>>>(mo_dst, cnt_mo, E_MO);
    k_count<<<(E_OM + 255) / 256, 256, 0, stream>>>(om_dst, cnt_om, E_OM);
    k_scan<<<3, 1024, 0, stream>>>(cnt_seq, off_seq, cnt_mo, off_mo, cnt_om, off_om);
    k_fill<<<(E_SEQ + 255) / 256, 256, 0, stream>>>(seq_dst, off_seq, pos_seq, E_SEQ);
    k_fill<<<(E_MO + 255) / 256, 256, 0, stream>>>(mo_dst, off_mo, pos_mo, E_MO);
    k_fill<<<(E_OM + 255) / 256, 256, 0, stream>>>(om_dst, off_om, pos_om, E_OM);

    // Projections + attention-score projections.
    k_gemm_op<<<1024, 256, 0, stream>>>(h_op, W_op_w, W_op_b, att_seq, att_om, att_mo,
                                        z_op, a_seq_src, a_seq_dst, a_om_src, a_mo_dst);
    k_gemm_mac<<<1000, 256, 0, stream>>>(h_mac, W_mac_w, W_mac_b, att_om, att_mo,
                                         z_mac, a_om_dst, a_mo_src);

    // Per-edge alpha written in bucket order.
    k_edge_alpha<<<(E_SEQ + 255) / 256, 256, 0, stream>>>(
        seq_src, seq_dst, feat_seq, a_seq_src, a_seq_dst, att_seq, pos_seq, alpha_seq, bs_seq, E_SEQ);
    k_edge_alpha<<<(E_MO + 255) / 256, 256, 0, stream>>>(
        mo_src, mo_dst, feat_mo, a_mo_src, a_mo_dst, att_mo, pos_mo, alpha_mo, bs_mo, E_MO);
    k_edge_alpha<<<(E_OM + 255) / 256, 256, 0, stream>>>(
        om_src, om_dst, feat_om, a_om_src, a_om_dst, att_om, pos_om, alpha_om, bs_om, E_OM);

    // Gather + residual + LN + ELU.
    k_gather_op<<<N_OP, 128, 0, stream>>>(bs_seq, alpha_seq, off_seq, cnt_seq,
                                          bs_mo, alpha_mo, off_mo, cnt_mo,
                                          z_op, z_mac, ln_op_g, ln_op_b, out_op);
    k_gather_mac<<<N_MAC, 128, 0, stream>>>(bs_om, alpha_om, off_om, cnt_om,
                                            z_op, z_mac, ln_mac_g, ln_mac_b, out_mac);
}

// Round 3
// 277.702 us; speedup vs baseline: 2.5740x; 1.4087x over previous
//
#include <hip/hip_runtime.h>

#define N_OP   50000
#define N_MAC  2000
#define IN_OP  64
#define IN_MAC 32
#define OUT    128
#define HEADS  4
#define DK     32
#define ATT_DIM 65
#define E_SEQ  150000
#define E_OM   300000
#define E_MO   300000
#define TOT_E  (E_SEQ + E_MO + E_OM)
#define EPS    1e-6f
#define LN_EPS 1e-5f

#define GB_OP  1024                    // op-gemm blocks in phase1
#define GB_MAC 250                     // mac-gemm blocks in phase1
#define CNT_B  ((TOT_E + 255) / 256)   // histogram blocks in phase1
#define CHUNK  1024                    // LDS index-staging chunk (ints)

typedef unsigned short ushort_t;
typedef unsigned int   uint_t;

__device__ __forceinline__ ushort_t f32_to_bf16_rtne(float f) {
    uint_t u = __float_as_uint(f);
    u += 0x7FFFu + ((u >> 16) & 1u);
    return (ushort_t)(u >> 16);
}

// ---------------------------------------------------------------------------
// Phase 1 (one kernel): op GEMM + projections | mac GEMM + projections |
// degree histograms for all 3 graphs. Grid regions by blockIdx.
// ---------------------------------------------------------------------------
__global__ void k_phase1(
    const float* __restrict__ h_op, const float* __restrict__ W_op, const float* __restrict__ b_op,
    const float* __restrict__ h_mac, const float* __restrict__ W_mac, const float* __restrict__ b_mac,
    const float* __restrict__ att_seq, const float* __restrict__ att_om, const float* __restrict__ att_mo,
    float* __restrict__ z_op, ushort_t* __restrict__ zb_op, float* __restrict__ z_mac,
    float* __restrict__ a_seq_src, float* __restrict__ a_seq_dst,
    float* __restrict__ a_om_src,  float* __restrict__ a_mo_dst,
    float* __restrict__ a_om_dst,  float* __restrict__ a_mo_src,
    const int* __restrict__ seq_dst, const int* __restrict__ mo_dst, const int* __restrict__ om_dst,
    int* __restrict__ cnt_seq, int* __restrict__ cnt_mo, int* __restrict__ cnt_om) {
    const int bid = blockIdx.x;
    const int t = threadIdx.x;
    __shared__ float hs[2][IN_OP];

    if (bid < GB_OP) {
        // ---- op GEMM: z = h_op @ W^T + b, 2 rows per iter ----
        const int col = t & 127, slot = t >> 7;
        float4 w[16];
        const float4* Wv = reinterpret_cast<const float4*>(W_op + col * IN_OP);
#pragma unroll
        for (int k = 0; k < 16; ++k) w[k] = Wv[k];
        const float bias = b_op[col];
        const int hd = col >> 5, l = col & 31;
        const float c1 = att_seq[hd * ATT_DIM + l];
        const float c2 = att_seq[hd * ATT_DIM + 32 + l];
        const float c3 = att_om[hd * ATT_DIM + l];
        const float c4 = att_mo[hd * ATT_DIM + 32 + l];
        for (int row0 = bid * 2; row0 < N_OP; row0 += GB_OP * 2) {
            __syncthreads();
            if (t < 128) hs[t >> 6][t & 63] = h_op[(size_t)(row0 + (t >> 6)) * IN_OP + (t & 63)];
            __syncthreads();
            const float4* hv = reinterpret_cast<const float4*>(hs[slot]);
            float acc = bias;
#pragma unroll
            for (int k = 0; k < 16; ++k) {
                float4 h4 = hv[k];
                acc += w[k].x * h4.x + w[k].y * h4.y + w[k].z * h4.z + w[k].w * h4.w;
            }
            const int row = row0 + slot;
            z_op[(size_t)row * OUT + col] = acc;
            zb_op[(size_t)row * OUT + col] = f32_to_bf16_rtne(acc);

            float p1 = acc * c1, p2 = acc * c2, p3 = acc * c3, p4 = acc * c4;
#pragma unroll
            for (int m = 16; m >= 1; m >>= 1) {
                p1 += __shfl_xor(p1, m);
                p2 += __shfl_xor(p2, m);
                p3 += __shfl_xor(p3, m);
                p4 += __shfl_xor(p4, m);
            }
            if (l == 0) {
                a_seq_src[row * HEADS + hd] = p1;
                a_seq_dst[row * HEADS + hd] = p2;
                a_om_src[row * HEADS + hd]  = p3;
                a_mo_dst[row * HEADS + hd]  = p4;
            }
        }
    } else if (bid < GB_OP + GB_MAC) {
        // ---- mac GEMM ----
        const int b2 = bid - GB_OP;
        const int col = t & 127, slot = t >> 7;
        float4 w[8];
        const float4* Wv = reinterpret_cast<const float4*>(W_mac + col * IN_MAC);
#pragma unroll
        for (int k = 0; k < 8; ++k) w[k] = Wv[k];
        const float bias = b_mac[col];
        const int hd = col >> 5, l = col & 31;
        const float c1 = att_om[hd * ATT_DIM + 32 + l];
        const float c2 = att_mo[hd * ATT_DIM + l];
        for (int row0 = b2 * 2; row0 < N_MAC; row0 += GB_MAC * 2) {
            __syncthreads();
            if (t < 64) hs[t >> 5][t & 31] = h_mac[(size_t)(row0 + (t >> 5)) * IN_MAC + (t & 31)];
            __syncthreads();
            const float4* hv = reinterpret_cast<const float4*>(hs[slot]);
            float acc = bias;
#pragma unroll
            for (int k = 0; k < 8; ++k) {
                float4 h4 = hv[k];
                acc += w[k].x * h4.x + w[k].y * h4.y + w[k].z * h4.z + w[k].w * h4.w;
            }
            const int row = row0 + slot;
            z_mac[(size_t)row * OUT + col] = acc;

            float p1 = acc * c1, p2 = acc * c2;
#pragma unroll
            for (int m = 16; m >= 1; m >>= 1) {
                p1 += __shfl_xor(p1, m);
                p2 += __shfl_xor(p2, m);
            }
            if (l == 0) {
                a_om_dst[row * HEADS + hd] = p1;
                a_mo_src[row * HEADS + hd] = p2;
            }
        }
    } else {
        // ---- degree histograms ----
        const int ge = (bid - GB_OP - GB_MAC) * 256 + t;
        if (ge < E_SEQ) atomicAdd(&cnt_seq[seq_dst[ge]], 1);
        else if (ge < E_SEQ + E_MO) atomicAdd(&cnt_mo[mo_dst[ge - E_SEQ]], 1);
        else if (ge < TOT_E) atomicAdd(&cnt_om[om_dst[ge - E_SEQ - E_MO]], 1);
    }
}

// ---------------------------------------------------------------------------
// Exclusive prefix scan, one 1024-thread block per array (grid.x = 3).
// ---------------------------------------------------------------------------
__global__ void k_scan(int* __restrict__ cnt_seq, int* __restrict__ off_seq,
                       int* __restrict__ cnt_mo,  int* __restrict__ off_mo,
                       int* __restrict__ cnt_om,  int* __restrict__ off_om) {
    int* cnt; int* off; int n;
    if (blockIdx.x == 0)      { cnt = cnt_seq; off = off_seq; n = N_OP; }
    else if (blockIdx.x == 1) { cnt = cnt_mo;  off = off_mo;  n = N_OP; }
    else                      { cnt = cnt_om;  off = off_om;  n = N_MAC; }
    const int t = threadIdx.x, lane = t & 63, w = t >> 6;
    __shared__ int wsum[16];
    __shared__ int carry;
    if (t == 0) carry = 0;
    __syncthreads();
    for (int base = 0; base < n; base += 1024) {
        const int i = base + t;
        const int v = (i < n) ? cnt[i] : 0;
        int x = v;
#pragma unroll
        for (int m = 1; m < 64; m <<= 1) {
            int y = __shfl_up(x, m);
            if (lane >= m) x += y;
        }
        if (lane == 63) wsum[w] = x;
        __syncthreads();
        if (t == 0) {
            int s = carry;
            for (int k = 0; k < 16; ++k) { int c = wsum[k]; wsum[k] = s; s += c; }
            carry = s;
        }
        __syncthreads();
        if (i < n) off[i] = x - v + wsum[w];
        __syncthreads();
    }
}

// ---------------------------------------------------------------------------
// Fill + alpha (fused, all 3 graphs): pos = atomicAdd(off[dst]); compute
// alpha = exp(clip(lrelu(a_src[s]+a_dst[d]+f*att64))); write in bucket order.
// ---------------------------------------------------------------------------
__global__ void k_fill_alpha(
    const int* __restrict__ seq_src, const int* __restrict__ seq_dst, const float* __restrict__ feat_seq,
    const int* __restrict__ mo_src,  const int* __restrict__ mo_dst,  const float* __restrict__ feat_mo,
    const int* __restrict__ om_src,  const int* __restrict__ om_dst,  const float* __restrict__ feat_om,
    const float* __restrict__ a_seq_src, const float* __restrict__ a_seq_dst,
    const float* __restrict__ a_mo_src,  const float* __restrict__ a_mo_dst,
    const float* __restrict__ a_om_src,  const float* __restrict__ a_om_dst,
    const float* __restrict__ att_seq, const float* __restrict__ att_mo, const float* __restrict__ att_om,
    int* __restrict__ off_seq, int* __restrict__ off_mo, int* __restrict__ off_om,
    float* __restrict__ al_seq, float* __restrict__ al_mo, float* __restrict__ al_om,
    int* __restrict__ bs_seq, int* __restrict__ bs_mo, int* __restrict__ bs_om) {
    const int ge = blockIdx.x * 256 + threadIdx.x;
    if (ge >= TOT_E) return;
    const int* src; const int* dst; const float* feat; const float* asrc; const float* adst;
    const float* att; int* off; float* abkt; int* bs; int e;
    if (ge < E_SEQ) {
        e = ge; src = seq_src; dst = seq_dst; feat = feat_seq;
        asrc = a_seq_src; adst = a_seq_dst; att = att_seq; off = off_seq; abkt = al_seq; bs = bs_seq;
    } else if (ge < E_SEQ + E_MO) {
        e = ge - E_SEQ; src = mo_src; dst = mo_dst; feat = feat_mo;
        asrc = a_mo_src; adst = a_mo_dst; att = att_mo; off = off_mo; abkt = al_mo; bs = bs_mo;
    } else {
        e = ge - E_SEQ - E_MO; src = om_src; dst = om_dst; feat = feat_om;
        asrc = a_om_src; adst = a_om_dst; att = att_om; off = off_om; abkt = al_om; bs = bs_om;
    }
    const int s = src[e], d = dst[e];
    const int pos = atomicAdd(&off[d], 1);
    const float f = feat[e];
    const float4 as = *reinterpret_cast<const float4*>(asrc + s * HEADS);
    const float4 ad = *reinterpret_cast<const float4*>(adst + d * HEADS);
    const float sc[4] = {as.x + ad.x, as.y + ad.y, as.z + ad.z, as.w + ad.w};
    float4 out;
    float* o = &out.x;
#pragma unroll
    for (int hh = 0; hh < 4; ++hh) {
        float v = sc[hh] + f * att[hh * ATT_DIM + 2 * DK];
        v = (v >= 0.f) ? v : 0.2f * v;
        v = fminf(fmaxf(v, -20.f), 20.f);
        o[hh] = expf(v);
    }
    *reinterpret_cast<float4*>(abkt + (size_t)pos * HEADS) = out;
    bs[pos] = s;
}

// ---------------------------------------------------------------------------
// Gather helpers: stage indices in LDS (kills the idx->row dependent chain),
// then unroll-8 over edges for 8 in-flight gather chains per wave.
// ---------------------------------------------------------------------------
__device__ __forceinline__ float seg_accum_bf16(const int* __restrict__ bs,
                                                const float* __restrict__ al,
                                                const ushort_t* __restrict__ zb,
                                                int start, int end, int t, int hd,
                                                int* lds) {
    float num = 0.f, den = 0.f;
    for (int base = start; base < end; base += CHUNK) {
        const int n = min(CHUNK, end - base);
        __syncthreads();
        for (int k = t; k < n; k += 128) lds[k] = bs[base + k];
        __syncthreads();
#pragma unroll 8
        for (int i = 0; i < n; ++i) {
            const int s = lds[i];
            const float a = al[(size_t)(base + i) * HEADS + hd];
            const float zf = __uint_as_float(((uint_t)zb[(size_t)s * OUT + t]) << 16);
            num += a * zf;
            den += a;
        }
    }
    return num / (den + EPS);
}

__device__ __forceinline__ float seg_accum_f32(const int* __restrict__ bs,
                                               const float* __restrict__ al,
                                               const float* __restrict__ z,
                                               int start, int end, int t, int hd,
                                               int* lds) {
    float num = 0.f, den = 0.f;
    for (int base = start; base < end; base += CHUNK) {
        const int n = min(CHUNK, end - base);
        __syncthreads();
        for (int k = t; k < n; k += 128) lds[k] = bs[base + k];
        __syncthreads();
#pragma unroll 8
        for (int i = 0; i < n; ++i) {
            const int s = lds[i];
            const float a = al[(size_t)(base + i) * HEADS + hd];
            num += a * z[(size_t)s * OUT + t];
            den += a;
        }
    }
    return num / (den + EPS);
}

__device__ __forceinline__ float ln_elu(float x, int t, const float* __restrict__ g,
                                        const float* __restrict__ bb, float* red) {
    float s = x;
#pragma unroll
    for (int m = 32; m >= 1; m >>= 1) s += __shfl_xor(s, m);
    if ((t & 63) == 0) red[t >> 6] = s;
    __syncthreads();
    const float mu = (red[0] + red[1]) * (1.0f / OUT);
    const float dx = x - mu;
    float q = dx * dx;
#pragma unroll
    for (int m = 32; m >= 1; m >>= 1) q += __shfl_xor(q, m);
    __syncthreads();
    if ((t & 63) == 0) red[t >> 6] = q;
    __syncthreads();
    const float var = (red[0] + red[1]) * (1.0f / OUT);
    float y = dx * rsqrtf(var + LN_EPS) * g[t] + bb[t];
    return (y > 0.f) ? y : expm1f(y);
}

// ---------------------------------------------------------------------------
// Gather (all rows): blocks [0,N_MAC) = mac rows (long poles first),
// [N_MAC, N_MAC+N_OP) = op rows. 128 threads = one output column each.
// ---------------------------------------------------------------------------
__global__ void k_gather(
    const int* __restrict__ bs_seq, const float* __restrict__ al_seq,
    const int* __restrict__ off_seq, const int* __restrict__ cnt_seq,
    const int* __restrict__ bs_mo, const float* __restrict__ al_mo,
    const int* __restrict__ off_mo, const int* __restrict__ cnt_mo,
    const int* __restrict__ bs_om, const float* __restrict__ al_om,
    const int* __restrict__ off_om, const int* __restrict__ cnt_om,
    const ushort_t* __restrict__ zb_op, const float* __restrict__ z_op,
    const float* __restrict__ z_mac,
    const float* __restrict__ g_op, const float* __restrict__ b_op,
    const float* __restrict__ g_mac, const float* __restrict__ b_mac,
    float* __restrict__ out_op, float* __restrict__ out_mac) {
    __shared__ int lds[CHUNK];
    __shared__ float red[2];
    const int bid = blockIdx.x;
    const int t = threadIdx.x;
    const int hd = t >> 5;
    if (bid < N_MAC) {
        const int d = bid;
        const int end = off_om[d], start = end - cnt_om[d];
        const float acc = seg_accum_bf16(bs_om, al_om, zb_op, start, end, t, hd, lds);
        const float x = acc + z_mac[(size_t)d * OUT + t];
        out_mac[(size_t)d * OUT + t] = ln_elu(x, t, g_mac, b_mac, red);
    } else {
        const int d = bid - N_MAC;
        const int e1 = off_seq[d], s1 = e1 - cnt_seq[d];
        float acc = seg_accum_bf16(bs_seq, al_seq, zb_op, s1, e1, t, hd, lds);
        const int e2 = off_mo[d], s2 = e2 - cnt_mo[d];
        acc += seg_accum_f32(bs_mo, al_mo, z_mac, s2, e2, t, hd, lds);
        const float x = acc + z_op[(size_t)d * OUT + t];
        out_op[(size_t)d * OUT + t] = ln_elu(x, t, g_op, b_op, red);
    }
}

extern "C" void kernel_launch(void* const* d_in, const int* in_sizes, int n_in,
                              void* d_out, int out_size, void* d_ws, size_t ws_size,
                              hipStream_t stream) {
    const float* h_op      = (const float*)d_in[0];
    const float* h_mac     = (const float*)d_in[1];
    const int*   seq_src   = (const int*)d_in[2];
    const int*   seq_dst   = (const int*)d_in[3];
    const int*   om_src    = (const int*)d_in[4];
    const int*   om_dst    = (const int*)d_in[5];
    const int*   mo_src    = (const int*)d_in[6];
    const int*   mo_dst    = (const int*)d_in[7];
    const float* feat_seq  = (const float*)d_in[8];
    const float* feat_om   = (const float*)d_in[9];
    const float* feat_mo   = (const float*)d_in[10];
    const float* W_op_w    = (const float*)d_in[11];
    const float* W_op_b    = (const float*)d_in[12];
    const float* W_mac_w   = (const float*)d_in[13];
    const float* W_mac_b   = (const float*)d_in[14];
    const float* att_seq   = (const float*)d_in[15];
    const float* att_om    = (const float*)d_in[16];
    const float* att_mo    = (const float*)d_in[17];
    const float* ln_op_g   = (const float*)d_in[18];
    const float* ln_op_b   = (const float*)d_in[19];
    const float* ln_mac_g  = (const float*)d_in[20];
    const float* ln_mac_b  = (const float*)d_in[21];

    float* p = (float*)d_ws;
    float* z_op      = p; p += (size_t)N_OP * OUT;
    float* z_mac     = p; p += (size_t)N_MAC * OUT;
    float* a_seq_src = p; p += N_OP * HEADS;
    float* a_seq_dst = p; p += N_OP * HEADS;
    float* a_om_src  = p; p += N_OP * HEADS;
    float* a_mo_dst  = p; p += N_OP * HEADS;
    float* a_om_dst  = p; p += N_MAC * HEADS;
    float* a_mo_src  = p; p += N_MAC * HEADS;
    float* al_seq    = p; p += (size_t)E_SEQ * HEADS;
    float* al_mo     = p; p += (size_t)E_MO * HEADS;
    float* al_om     = p; p += (size_t)E_OM * HEADS;
    ushort_t* zb_op  = (ushort_t*)p; p += (size_t)N_OP * OUT / 2;  // 2 ushort per float slot
    int* q = (int*)p;
    int* cnt_seq = q; q += N_OP;     // cnt_* contiguous for one memset
    int* cnt_mo  = q; q += N_OP;
    int* cnt_om  = q; q += N_MAC;
    int* off_seq = q; q += N_OP;
    int* off_mo  = q; q += N_OP;
    int* off_om  = q; q += N_MAC;
    int* bs_seq  = q; q += E_SEQ;
    int* bs_mo   = q; q += E_MO;
    int* bs_om   = q; q += E_OM;

    float* out_op  = (float*)d_out;
    float* out_mac = (float*)d_out + (size_t)N_OP * OUT;

    hipMemsetAsync(cnt_seq, 0, (size_t)(2 * N_OP + N_MAC) * sizeof(int), stream);

    k_phase1<<<GB_OP + GB_MAC + CNT_B, 256, 0, stream>>>(
        h_op, W_op_w, W_op_b, h_mac, W_mac_w, W_mac_b,
        att_seq, att_om, att_mo,
        z_op, zb_op, z_mac,
        a_seq_src, a_seq_dst, a_om_src, a_mo_dst, a_om_dst, a_mo_src,
        seq_dst, mo_dst, om_dst, cnt_seq, cnt_mo, cnt_om);

    k_scan<<<3, 1024, 0, stream>>>(cnt_seq, off_seq, cnt_mo, off_mo, cnt_om, off_om);

    k_fill_alpha<<<CNT_B, 256, 0, stream>>>(
        seq_src, seq_dst, feat_seq, mo_src, mo_dst, feat_mo, om_src, om_dst, feat_om,
        a_seq_src, a_seq_dst, a_mo_src, a_mo_dst, a_om_src, a_om_dst,
        att_seq, att_mo, att_om,
        off_seq, off_mo, off_om,
        al_seq, al_mo, al_om, bs_seq, bs_mo, bs_om);

    k_gather<<<N_MAC + N_OP, 128, 0, stream>>>(
        bs_seq, al_seq, off_seq, cnt_seq,
        bs_mo, al_mo, off_mo, cnt_mo,
        bs_om, al_om, off_om, cnt_om,
        zb_op, z_op, z_mac,
        ln_op_g, ln_op_b, ln_mac_g, ln_mac_b,
        out_op, out_mac);
}

// Round 4
// 241.619 us; speedup vs baseline: 2.9584x; 1.1493x over previous
//
#include <hip/hip_runtime.h>

#define N_OP   50000
#define N_MAC  2000
#define IN_OP  64
#define IN_MAC 32
#define OUT    128
#define HEADS  4
#define DK     32
#define ATT_DIM 65
#define E_SEQ  150000
#define E_OM   300000
#define E_MO   300000
#define TOT_E  (E_SEQ + E_MO + E_OM)
#define EPS    1e-6f
#define LN_EPS 1e-5f

// phase1 grid regions
#define GB_OP   1024                   // op gemm blocks
#define GB_MAC  125                    // mac gemm blocks (125 tiles of 16 rows)
#define PB_OP   512                    // op projection blocks
#define PB_MAC  63                     // mac projection blocks
#define CNT_B   ((TOT_E + 255) / 256)  // histogram blocks
#define T_OP    (N_OP / 16)            // 3125 row tiles
#define T_MAC   (N_MAC / 16)           // 125

// alloc grid regions (256 entries per block)
#define AB_SEQ  ((N_OP + 255) / 256)   // 196
#define AB_MO   ((N_OP + 255) / 256)   // 196
#define AB_OM   ((N_MAC + 255) / 256)  // 8

typedef unsigned short ushort_t;
typedef unsigned int   uint_t;

__device__ __forceinline__ ushort_t f32_to_bf16_rtne(float f) {
    uint_t u = __float_as_uint(f);
    u += 0x7FFFu + ((u >> 16) & 1u);
    return (ushort_t)(u >> 16);
}

// ---------------------------------------------------------------------------
// Prep: fold attention vectors through W so projections become tiny GEMMs
// from h directly.  U_op[j][k], j = pr*4+hd:  pr0=seq_src(att[0:32]),
// pr1=seq_dst(att[32:64]), pr2=om_src, pr3=mo_dst.  c_op[j] = bias fold.
// U_mac[j][k], j = pr*4+hd: pr0=om_dst(att_om[32:64]), pr1=mo_src(att_mo[0:32]).
// ---------------------------------------------------------------------------
__global__ void k_prep(const float* __restrict__ W_op, const float* __restrict__ b_op,
                       const float* __restrict__ W_mac, const float* __restrict__ b_mac,
                       const float* __restrict__ att_seq, const float* __restrict__ att_om,
                       const float* __restrict__ att_mo,
                       float* __restrict__ U_op, float* __restrict__ c_op,
                       float* __restrict__ U_mac, float* __restrict__ c_mac) {
    const int t = threadIdx.x;
    for (int idx = t; idx < 16 * IN_OP; idx += 256) {
        const int j = idx >> 6, k = idx & 63;
        const int hd = j & 3, pr = j >> 2;
        const float* att = (pr <= 1) ? att_seq : (pr == 2 ? att_om : att_mo);
        const int off = (pr == 1 || pr == 3) ? 32 : 0;
        float s = 0.f;
        for (int l = 0; l < 32; ++l)
            s += att[hd * ATT_DIM + off + l] * W_op[(hd * 32 + l) * IN_OP + k];
        U_op[idx] = s;
    }
    if (t < 16) {
        const int hd = t & 3, pr = t >> 2;
        const float* att = (pr <= 1) ? att_seq : (pr == 2 ? att_om : att_mo);
        const int off = (pr == 1 || pr == 3) ? 32 : 0;
        float s = 0.f;
        for (int l = 0; l < 32; ++l) s += att[hd * ATT_DIM + off + l] * b_op[hd * 32 + l];
        c_op[t] = s;
    }
    for (int idx = t; idx < 8 * IN_MAC; idx += 256) {
        const int j = idx >> 5, k = idx & 31;
        const int hd = j & 3, pr = j >> 2;
        const float* att = (pr == 0) ? att_om : att_mo;
        const int off = (pr == 0) ? 32 : 0;
        float s = 0.f;
        for (int l = 0; l < 32; ++l)
            s += att[hd * ATT_DIM + off + l] * W_mac[(hd * 32 + l) * IN_MAC + k];
        U_mac[idx] = s;
    }
    if (t < 8) {
        const int hd = t & 3, pr = t >> 2;
        const float* att = (pr == 0) ? att_om : att_mo;
        const int off = (pr == 0) ? 32 : 0;
        float s = 0.f;
        for (int l = 0; l < 32; ++l) s += att[hd * ATT_DIM + off + l] * b_mac[hd * 32 + l];
        c_mac[t] = s;
    }
}

// ---------------------------------------------------------------------------
// Phase 1: [A] op GEMM (z+zb, 16 rows/barrier-pair) | [B] mac GEMM |
// [C] op projections h@U_op | [D] mac projections | [E] degree histograms.
// ---------------------------------------------------------------------------
__global__ void k_phase1(
    const float* __restrict__ h_op, const float* __restrict__ W_op, const float* __restrict__ b_op,
    const float* __restrict__ h_mac, const float* __restrict__ W_mac, const float* __restrict__ b_mac,
    const float* __restrict__ U_op, const float* __restrict__ c_op,
    const float* __restrict__ U_mac, const float* __restrict__ c_mac,
    float* __restrict__ z_op, ushort_t* __restrict__ zb_op,
    float* __restrict__ z_mac, ushort_t* __restrict__ zb_mac,
    float* __restrict__ p_op, float* __restrict__ p_mac,
    const int* __restrict__ seq_dst, const int* __restrict__ mo_dst, const int* __restrict__ om_dst,
    int* __restrict__ cnt_seq, int* __restrict__ cnt_mo, int* __restrict__ cnt_om) {
    const int bid = blockIdx.x;
    const int t = threadIdx.x;
    __shared__ float smem[16 * 64];

    if (bid < GB_OP) {
        // ---- [A] op GEMM ----
        const int col = t & 127, slot = t >> 7;
        float4 w[16];
        const float4* Wv = reinterpret_cast<const float4*>(W_op + col * IN_OP);
#pragma unroll
        for (int k = 0; k < 16; ++k) w[k] = Wv[k];
        const float bias = b_op[col];
        for (int tile = bid; tile < T_OP; tile += GB_OP) {
            const int row0 = tile * 16;
            __syncthreads();
            *reinterpret_cast<float4*>(&smem[t * 4]) =
                *reinterpret_cast<const float4*>(h_op + (size_t)row0 * IN_OP + t * 4);
            __syncthreads();
#pragma unroll
            for (int r8 = 0; r8 < 8; ++r8) {
                const int rr = slot * 8 + r8;
                const float4* hv = reinterpret_cast<const float4*>(&smem[rr * IN_OP]);
                float acc = bias;
#pragma unroll
                for (int k = 0; k < 16; ++k) {
                    float4 h4 = hv[k];
                    acc += w[k].x * h4.x + w[k].y * h4.y + w[k].z * h4.z + w[k].w * h4.w;
                }
                const size_t o = (size_t)(row0 + rr) * OUT + col;
                z_op[o] = acc;
                zb_op[o] = f32_to_bf16_rtne(acc);
            }
        }
    } else if (bid < GB_OP + GB_MAC) {
        // ---- [B] mac GEMM ----
        const int tile = bid - GB_OP;
        const int col = t & 127, slot = t >> 7;
        float4 w[8];
        const float4* Wv = reinterpret_cast<const float4*>(W_mac + col * IN_MAC);
#pragma unroll
        for (int k = 0; k < 8; ++k) w[k] = Wv[k];
        const float bias = b_mac[col];
        const int row0 = tile * 16;
        if (t < 128)
            *reinterpret_cast<float4*>(&smem[t * 4]) =
                *reinterpret_cast<const float4*>(h_mac + (size_t)row0 * IN_MAC + t * 4);
        __syncthreads();
#pragma unroll
        for (int r8 = 0; r8 < 8; ++r8) {
            const int rr = slot * 8 + r8;
            const float4* hv = reinterpret_cast<const float4*>(&smem[rr * IN_MAC]);
            float acc = bias;
#pragma unroll
            for (int k = 0; k < 8; ++k) {
                float4 h4 = hv[k];
                acc += w[k].x * h4.x + w[k].y * h4.y + w[k].z * h4.z + w[k].w * h4.w;
            }
            const size_t o = (size_t)(row0 + rr) * OUT + col;
            z_mac[o] = acc;
            zb_mac[o] = f32_to_bf16_rtne(acc);
        }
    } else if (bid < GB_OP + GB_MAC + PB_OP) {
        // ---- [C] op projections: p_op[row][16] = h_op[row] @ U_op^T + c_op ----
        const int b2 = bid - GB_OP - GB_MAC;
        const int r = t >> 4, j = t & 15;
        float4 u[16];
        const float4* Uv = reinterpret_cast<const float4*>(U_op + j * IN_OP);
#pragma unroll
        for (int k = 0; k < 16; ++k) u[k] = Uv[k];
        const float cj = c_op[j];
        for (int tile = b2; tile < T_OP; tile += PB_OP) {
            const int row0 = tile * 16;
            __syncthreads();
            *reinterpret_cast<float4*>(&smem[t * 4]) =
                *reinterpret_cast<const float4*>(h_op + (size_t)row0 * IN_OP + t * 4);
            __syncthreads();
            const float4* hv = reinterpret_cast<const float4*>(&smem[r * IN_OP]);
            float acc = cj;
#pragma unroll
            for (int k = 0; k < 16; ++k) {
                float4 h4 = hv[k];
                acc += u[k].x * h4.x + u[k].y * h4.y + u[k].z * h4.z + u[k].w * h4.w;
            }
            p_op[(size_t)(row0 + r) * 16 + j] = acc;
        }
    } else if (bid < GB_OP + GB_MAC + PB_OP + PB_MAC) {
        // ---- [D] mac projections: p_mac[row][8] = h_mac[row] @ U_mac^T + c_mac ----
        const int b2 = bid - GB_OP - GB_MAC - PB_OP;
        const int r = t >> 3, j = t & 7;      // 32 rows x 8 outputs
        float4 u[8];
        const float4* Uv = reinterpret_cast<const float4*>(U_mac + j * IN_MAC);
#pragma unroll
        for (int k = 0; k < 8; ++k) u[k] = Uv[k];
        const float cj = c_mac[j];
        const int row0 = b2 * 32;
        *reinterpret_cast<float4*>(&smem[t * 4]) =
            *reinterpret_cast<const float4*>(h_mac + (size_t)row0 * IN_MAC + t * 4);
        __syncthreads();
        const int row = row0 + r;
        if (row < N_MAC) {
            const float4* hv = reinterpret_cast<const float4*>(&smem[r * IN_MAC]);
            float acc = cj;
#pragma unroll
            for (int k = 0; k < 8; ++k) {
                float4 h4 = hv[k];
                acc += u[k].x * h4.x + u[k].y * h4.y + u[k].z * h4.z + u[k].w * h4.w;
            }
            p_mac[(size_t)row * 8 + j] = acc;
        }
    } else {
        // ---- [E] degree histograms ----
        const int ge = (bid - GB_OP - GB_MAC - PB_OP - PB_MAC) * 256 + t;
        if (ge < E_SEQ) atomicAdd(&cnt_seq[seq_dst[ge]], 1);
        else if (ge < E_SEQ + E_MO) atomicAdd(&cnt_mo[mo_dst[ge - E_SEQ]], 1);
        else if (ge < TOT_E) atomicAdd(&cnt_om[om_dst[ge - E_SEQ - E_MO]], 1);
    }
}

// ---------------------------------------------------------------------------
// Range allocation (replaces ordered scan — bucket order is irrelevant):
// per-wave inclusive scan of counts, one atomicAdd per wave on per-graph ctr.
// Writes sta[] (range start, for gather) and off[] (running cursor, for fill).
// ---------------------------------------------------------------------------
__global__ void k_alloc(const int* __restrict__ cnt_seq, int* __restrict__ sta_seq, int* __restrict__ off_seq,
                        const int* __restrict__ cnt_mo,  int* __restrict__ sta_mo,  int* __restrict__ off_mo,
                        const int* __restrict__ cnt_om,  int* __restrict__ sta_om,  int* __restrict__ off_om,
                        int* __restrict__ ctr) {
    const int b = blockIdx.x, t = threadIdx.x;
    const int* cnt; int* sta; int* off; int n, g, lb;
    if (b < AB_SEQ)            { cnt = cnt_seq; sta = sta_seq; off = off_seq; n = N_OP;  g = 0; lb = b; }
    else if (b < AB_SEQ + AB_MO){ cnt = cnt_mo;  sta = sta_mo;  off = off_mo;  n = N_OP;  g = 1; lb = b - AB_SEQ; }
    else                       { cnt = cnt_om;  sta = sta_om;  off = off_om;  n = N_MAC; g = 2; lb = b - AB_SEQ - AB_MO; }
    const int d = lb * 256 + t;
    const int lane = t & 63;
    const int v = (d < n) ? cnt[d] : 0;
    int x = v;
#pragma unroll
    for (int m = 1; m < 64; m <<= 1) {
        int y = __shfl_up(x, m);
        if (lane >= m) x += y;
    }
    int base = 0;
    if (lane == 63) base = atomicAdd(&ctr[g], x);
    base = __shfl(base, 63);
    if (d < n) {
        const int s = base + x - v;
        sta[d] = s;
        off[d] = s;
    }
}

// ---------------------------------------------------------------------------
// Fill + alpha (all 3 graphs): pos = atomicAdd(off[dst]);
// alpha = exp(clip(lrelu(p_src + p_dst + f*att64))); write in bucket order.
// ---------------------------------------------------------------------------
__global__ void k_fill_alpha(
    const int* __restrict__ seq_src, const int* __restrict__ seq_dst, const float* __restrict__ feat_seq,
    const int* __restrict__ mo_src,  const int* __restrict__ mo_dst,  const float* __restrict__ feat_mo,
    const int* __restrict__ om_src,  const int* __restrict__ om_dst,  const float* __restrict__ feat_om,
    const float* __restrict__ p_op, const float* __restrict__ p_mac,
    const float* __restrict__ att_seq, const float* __restrict__ att_mo, const float* __restrict__ att_om,
    int* __restrict__ off_seq, int* __restrict__ off_mo, int* __restrict__ off_om,
    float* __restrict__ al_seq, float* __restrict__ al_mo, float* __restrict__ al_om,
    int* __restrict__ bs_seq, int* __restrict__ bs_mo, int* __restrict__ bs_om) {
    const int ge = blockIdx.x * 256 + threadIdx.x;
    if (ge >= TOT_E) return;
    int s, d, pos;
    float f;
    float4 as, ad, aw;
    int* bs; float* abkt;
    if (ge < E_SEQ) {
        const int e = ge;
        s = seq_src[e]; d = seq_dst[e]; f = feat_seq[e];
        as = *reinterpret_cast<const float4*>(p_op + (size_t)s * 16 + 0);
        ad = *reinterpret_cast<const float4*>(p_op + (size_t)d * 16 + 4);
        aw = make_float4(att_seq[64], att_seq[ATT_DIM + 64], att_seq[2 * ATT_DIM + 64], att_seq[3 * ATT_DIM + 64]);
        pos = atomicAdd(&off_seq[d], 1);
        abkt = al_seq; bs = bs_seq;
    } else if (ge < E_SEQ + E_MO) {
        const int e = ge - E_SEQ;
        s = mo_src[e]; d = mo_dst[e]; f = feat_mo[e];
        as = *reinterpret_cast<const float4*>(p_mac + (size_t)s * 8 + 4);
        ad = *reinterpret_cast<const float4*>(p_op + (size_t)d * 16 + 12);
        aw = make_float4(att_mo[64], att_mo[ATT_DIM + 64], att_mo[2 * ATT_DIM + 64], att_mo[3 * ATT_DIM + 64]);
        pos = atomicAdd(&off_mo[d], 1);
        abkt = al_mo; bs = bs_mo;
    } else {
        const int e = ge - E_SEQ - E_MO;
        s = om_src[e]; d = om_dst[e]; f = feat_om[e];
        as = *reinterpret_cast<const float4*>(p_op + (size_t)s * 16 + 8);
        ad = *reinterpret_cast<const float4*>(p_mac + (size_t)d * 8 + 0);
        aw = make_float4(att_om[64], att_om[ATT_DIM + 64], att_om[2 * ATT_DIM + 64], att_om[3 * ATT_DIM + 64]);
        pos = atomicAdd(&off_om[d], 1);
        abkt = al_om; bs = bs_om;
    }
    const float sc[4] = {as.x + ad.x + f * aw.x, as.y + ad.y + f * aw.y,
                         as.z + ad.z + f * aw.z, as.w + ad.w + f * aw.w};
    float4 out;
    float* o = &out.x;
#pragma unroll
    for (int hh = 0; hh < 4; ++hh) {
        float v = sc[hh];
        v = (v >= 0.f) ? v : 0.2f * v;
        v = fminf(fmaxf(v, -20.f), 20.f);
        o[hh] = expf(v);
    }
    *reinterpret_cast<float4*>(abkt + (size_t)pos * HEADS) = out;
    bs[pos] = s;
}

// ---------------------------------------------------------------------------
// Gather: one WAVE per destination row, 2 cols per lane (ushort2 bf16 loads).
// Indices preloaded per-lane, broadcast via shfl. No LDS, no barriers.
// ---------------------------------------------------------------------------
__device__ __forceinline__ void seg2(const int* __restrict__ bs, const float* __restrict__ al,
                                     const ushort_t* __restrict__ zb,
                                     int s0, int e0, int lane, int hd, int col2,
                                     float& out0, float& out1) {
    float num0 = 0.f, num1 = 0.f, den = 0.f;
    for (int base = s0; base < e0; base += 64) {
        int nn = e0 - base;
        if (nn > 64) nn = 64;
        int sidx = 0;
        if (base + lane < e0) sidx = bs[base + lane];
#pragma unroll 4
        for (int i = 0; i < nn; ++i) {
            const int s = __shfl(sidx, i);
            const float a = al[(size_t)(base + i) * HEADS + hd];
            const uint_t zz = *reinterpret_cast<const uint_t*>(zb + (size_t)s * OUT + col2);
            num0 = fmaf(a, __uint_as_float(zz << 16), num0);
            num1 = fmaf(a, __uint_as_float(zz & 0xffff0000u), num1);
            den += a;
        }
    }
    const float inv = 1.0f / (den + EPS);
    out0 += num0 * inv;
    out1 += num1 * inv;
}

__global__ void k_gather(
    const int* __restrict__ bs_seq, const float* __restrict__ al_seq,
    const int* __restrict__ sta_seq, const int* __restrict__ off_seq,
    const int* __restrict__ bs_mo, const float* __restrict__ al_mo,
    const int* __restrict__ sta_mo, const int* __restrict__ off_mo,
    const int* __restrict__ bs_om, const float* __restrict__ al_om,
    const int* __restrict__ sta_om, const int* __restrict__ off_om,
    const ushort_t* __restrict__ zb_op, const ushort_t* __restrict__ zb_mac,
    const float* __restrict__ z_op, const float* __restrict__ z_mac,
    const float* __restrict__ g_op, const float* __restrict__ b_op,
    const float* __restrict__ g_mac, const float* __restrict__ b_mac,
    float* __restrict__ out_op, float* __restrict__ out_mac) {
    const int w = threadIdx.x >> 6, lane = threadIdx.x & 63;
    const int R = blockIdx.x * 4 + w;          // [0,N_MAC): mac rows; then op rows
    const int hd = lane >> 4;
    const int col2 = lane * 2;

    float acc0 = 0.f, acc1 = 0.f;
    const float* zres;
    const float* g; const float* bb;
    float* out;
    int d;
    if (R < N_MAC) {
        d = R;
        seg2(bs_om, al_om, zb_op, sta_om[d], off_om[d], lane, hd, col2, acc0, acc1);
        zres = z_mac; g = g_mac; bb = b_mac; out = out_mac;
    } else {
        d = R - N_MAC;
        seg2(bs_seq, al_seq, zb_op, sta_seq[d], off_seq[d], lane, hd, col2, acc0, acc1);
        seg2(bs_mo, al_mo, zb_mac, sta_mo[d], off_mo[d], lane, hd, col2, acc0, acc1);
        zres = z_op; g = g_op; bb = b_op; out = out_op;
    }
    const float2 zr = *reinterpret_cast<const float2*>(zres + (size_t)d * OUT + col2);
    float x0 = acc0 + zr.x;
    float x1 = acc1 + zr.y;

    // wave LayerNorm over 128 cols (2 per lane)
    float s = x0 + x1;
#pragma unroll
    for (int m = 32; m >= 1; m >>= 1) s += __shfl_xor(s, m);
    const float mu = s * (1.0f / OUT);
    const float dx0 = x0 - mu, dx1 = x1 - mu;
    float q = dx0 * dx0 + dx1 * dx1;
#pragma unroll
    for (int m = 32; m >= 1; m >>= 1) q += __shfl_xor(q, m);
    const float r = rsqrtf(q * (1.0f / OUT) + LN_EPS);
    const float2 g2 = *reinterpret_cast<const float2*>(g + col2);
    const float2 b2 = *reinterpret_cast<const float2*>(bb + col2);
    float y0 = dx0 * r * g2.x + b2.x;
    float y1 = dx1 * r * g2.y + b2.y;
    y0 = (y0 > 0.f) ? y0 : expm1f(y0);
    y1 = (y1 > 0.f) ? y1 : expm1f(y1);
    float2 o2 = make_float2(y0, y1);
    *reinterpret_cast<float2*>(out + (size_t)d * OUT + col2) = o2;
}

extern "C" void kernel_launch(void* const* d_in, const int* in_sizes, int n_in,
                              void* d_out, int out_size, void* d_ws, size_t ws_size,
                              hipStream_t stream) {
    const float* h_op      = (const float*)d_in[0];
    const float* h_mac     = (const float*)d_in[1];
    const int*   seq_src   = (const int*)d_in[2];
    const int*   seq_dst   = (const int*)d_in[3];
    const int*   om_src    = (const int*)d_in[4];
    const int*   om_dst    = (const int*)d_in[5];
    const int*   mo_src    = (const int*)d_in[6];
    const int*   mo_dst    = (const int*)d_in[7];
    const float* feat_seq  = (const float*)d_in[8];
    const float* feat_om   = (const float*)d_in[9];
    const float* feat_mo   = (const float*)d_in[10];
    const float* W_op_w    = (const float*)d_in[11];
    const float* W_op_b    = (const float*)d_in[12];
    const float* W_mac_w   = (const float*)d_in[13];
    const float* W_mac_b   = (const float*)d_in[14];
    const float* att_seq   = (const float*)d_in[15];
    const float* att_om    = (const float*)d_in[16];
    const float* att_mo    = (const float*)d_in[17];
    const float* ln_op_g   = (const float*)d_in[18];
    const float* ln_op_b   = (const float*)d_in[19];
    const float* ln_mac_g  = (const float*)d_in[20];
    const float* ln_mac_b  = (const float*)d_in[21];

    float* p = (float*)d_ws;
    float* z_op   = p; p += (size_t)N_OP * OUT;
    float* z_mac  = p; p += (size_t)N_MAC * OUT;
    float* p_op   = p; p += (size_t)N_OP * 16;
    float* p_mac  = p; p += (size_t)N_MAC * 8;
    float* al_seq = p; p += (size_t)E_SEQ * HEADS;
    float* al_mo  = p; p += (size_t)E_MO * HEADS;
    float* al_om  = p; p += (size_t)E_OM * HEADS;
    float* U_op   = p; p += 16 * IN_OP;
    float* c_op   = p; p += 16;
    float* U_mac  = p; p += 8 * IN_MAC;
    float* c_mac  = p; p += 16;                     // padded to keep 16B alignment
    ushort_t* zb_op  = (ushort_t*)p; p += (size_t)N_OP * OUT / 2;
    ushort_t* zb_mac = (ushort_t*)p; p += (size_t)N_MAC * OUT / 2;
    int* q = (int*)p;
    int* cnt_seq = q; q += N_OP;    // cnt_* + ctr contiguous for one memset
    int* cnt_mo  = q; q += N_OP;
    int* cnt_om  = q; q += N_MAC;
    int* ctr     = q; q += 4;
    int* sta_seq = q; q += N_OP;
    int* sta_mo  = q; q += N_OP;
    int* sta_om  = q; q += N_MAC;
    int* off_seq = q; q += N_OP;
    int* off_mo  = q; q += N_OP;
    int* off_om  = q; q += N_MAC;
    int* bs_seq  = q; q += E_SEQ;
    int* bs_mo   = q; q += E_MO;
    int* bs_om   = q; q += E_OM;

    float* out_op  = (float*)d_out;
    float* out_mac = (float*)d_out + (size_t)N_OP * OUT;

    hipMemsetAsync(cnt_seq, 0, (size_t)(2 * N_OP + N_MAC + 4) * sizeof(int), stream);

    k_prep<<<1, 256, 0, stream>>>(W_op_w, W_op_b, W_mac_w, W_mac_b,
                                  att_seq, att_om, att_mo, U_op, c_op, U_mac, c_mac);

    k_phase1<<<GB_OP + GB_MAC + PB_OP + PB_MAC + CNT_B, 256, 0, stream>>>(
        h_op, W_op_w, W_op_b, h_mac, W_mac_w, W_mac_b,
        U_op, c_op, U_mac, c_mac,
        z_op, zb_op, z_mac, zb_mac, p_op, p_mac,
        seq_dst, mo_dst, om_dst, cnt_seq, cnt_mo, cnt_om);

    k_alloc<<<AB_SEQ + AB_MO + AB_OM, 256, 0, stream>>>(
        cnt_seq, sta_seq, off_seq, cnt_mo, sta_mo, off_mo, cnt_om, sta_om, off_om, ctr);

    k_fill_alpha<<<CNT_B, 256, 0, stream>>>(
        seq_src, seq_dst, feat_seq, mo_src, mo_dst, feat_mo, om_src, om_dst, feat_om,
        p_op, p_mac, att_seq, att_mo, att_om,
        off_seq, off_mo, off_om,
        al_seq, al_mo, al_om, bs_seq, bs_mo, bs_om);

    k_gather<<<(N_MAC + N_OP) / 4, 256, 0, stream>>>(
        bs_seq, al_seq, sta_seq, off_seq,
        bs_mo, al_mo, sta_mo, off_mo,
        bs_om, al_om, sta_om, off_om,
        zb_op, zb_mac, z_op, z_mac,
        ln_op_g, ln_op_b, ln_mac_g, ln_mac_b,
        out_op, out_mac);
}